// Round 2
// baseline (316.789 us; speedup 1.0000x reference)
//
#include <hip/hip_runtime.h>
#include <hip/hip_bf16.h>
#include <stdint.h>

typedef __bf16 bf16;
typedef bf16 bf16x4 __attribute__((ext_vector_type(4)));
typedef bf16 bf16x8 __attribute__((ext_vector_type(8)));
typedef float f32x4 __attribute__((ext_vector_type(4)));
typedef float fv4 __attribute__((ext_vector_type(4)));   // native clang vector for nontemporal builtins

#define FIN   128
#define FOUT  128
#define FANIN 640
#define BM    128
#define BK    64      // K sub-chunk (bf16 elems); A LDS tile 16KB, x2 dbuf = 32KB total

__device__ __forceinline__ void async16(const void* g, void* l) {
    __builtin_amdgcn_global_load_lds((const __attribute__((address_space(1))) void*)g,
                                     (__attribute__((address_space(3))) void*)l,
                                     16, 0, 0);
}

// ---------------- convert fp32 -> bf16 (x and W), non-temporal reads ----------------
__global__ __launch_bounds__(256)
void convert_kernel(const float* __restrict__ x, const float* __restrict__ W,
                    bf16* __restrict__ xb, bf16* __restrict__ wb,
                    long nx4, long ntot4)
{
    long i = (long)blockIdx.x * 256 + threadIdx.x;   // float4 index
    if (i >= ntot4) return;
    fv4 v;
    bf16* dst;
    if (i < nx4) { v = __builtin_nontemporal_load((const fv4*)x + i); dst = xb + i * 4; }
    else         { long k = i - nx4;
                   v = __builtin_nontemporal_load((const fv4*)W + k); dst = wb + k * 4; }
    bf16x4 h = { (bf16)v.x, (bf16)v.y, (bf16)v.z, (bf16)v.w };
    *(bf16x4*)dst = h;
}

// ---------------- gather-GEMM v3: A-only LDS (dbuf, 32KB), B direct from global ----------------
// Round-1 lesson: 64KB LDS halved blocks/CU and regressed. Fix: drop Bsm entirely —
// W is 160KB, L2-hot; each lane's B fragment is a contiguous 16B global load
// (row*1280 + c*128 + s*64 + quad*16). LDS = A double-buffer only (2x16KB = 32KB,
// 4 blocks/CU). One barrier per chunk. B-reg loads issued BEFORE the gather STAGE so
// compiler vmcnt waits for b (oldest-first retirement) never drain in-flight gathers.
// Gather for chunk c+1 issued right after barrier(c), waited a full compute phase later.
__global__ __launch_bounds__(256, 4)
void mcc_mfma(const bf16* __restrict__ xb, const int* __restrict__ nbr,
              const bf16* __restrict__ wb, const float* __restrict__ bias,
              float* __restrict__ out, int N)
{
    __shared__ __align__(16) bf16 Asm[2][BM][BK];     // 32 KB

    const int tid  = threadIdx.x;
    const int wave = tid >> 6;
    const int lane = tid & 63;
    const int quad = lane >> 4;
    const int l16  = lane & 15;
    const int wr   = wave >> 1;      // wave row 0..1 (64 out-rows each)
    const int wc   = wave & 1;       // wave col 0..1 (64 out-cols each)
    const int m0   = blockIdx.x * BM;

    const int r8 = lane >> 3;        // row-within-staging-instr 0..7
    const int c8 = lane & 7;         // 16B chunk 0..7
    const int sw = (c8 ^ r8) << 4;   // swizzled chunk byte offset

    // preload gather row ids into VGPRs: gsel[i][j], i = staging instr, j = slot
    int gsel[4][5];
    #pragma unroll
    for (int i = 0; i < 4; ++i) {
        int tr   = wave * 32 + i * 8 + r8;
        int node = m0 + tr;
        node = node < N ? node : N - 1;
        gsel[i][0] = node;
        #pragma unroll
        for (int jj = 1; jj < 5; ++jj)
            gsel[i][jj] = nbr[(long)node * 4 + (jj - 1)];   // 8 lanes share addr (broadcast)
    }
    // drain nbr loads so loop-time vmem queue holds only b-loads + async16s
    asm volatile("s_waitcnt vmcnt(0)" ::: "memory");

    // B fragment 32-bit row offsets (SGPR-base + voffset addressing; imm13 holds c*128+s*64)
    int boff[4];
    #pragma unroll
    for (int ni = 0; ni < 4; ++ni)
        boff[ni] = (wc * 64 + ni * 16 + l16) * (FANIN * 2) + quad * 16;
    const char* wbc = (const char*)wb;

    f32x4 acc[4][4] = {};

    // stage chunk k's A rows (j = k>>1, h = k&1) into LDS buffer pb: 4 async16 per wave
    #define STAGEA(pb, k) do {                                                             \
        const int j_ = (k) >> 1, h_ = (k) & 1;                                             \
        _Pragma("unroll")                                                                  \
        for (int i = 0; i < 4; ++i) {                                                      \
            const char* ga = (const char*)xb + ((long)gsel[i][j_] << 8) + h_ * 128 + sw;   \
            async16(ga, &Asm[pb][wave * 32 + i * 8][0]);                                   \
        }                                                                                  \
    } while (0)

    STAGEA(0, 0);

    #pragma unroll
    for (int c = 0; c < 10; ++c) {
        const int cur = c & 1;

        // A[c] landed? (only this wave's 4 async16 outstanding here)
        asm volatile("s_waitcnt vmcnt(0)" ::: "memory");
        __builtin_amdgcn_s_barrier();               // all waves' A[c] rows visible
        asm volatile("" ::: "memory");

        // ---- B fragments straight from global (L2-hot weights); issue FIRST ----
        bf16x8 b0[4], b1[4];
        #pragma unroll
        for (int ni = 0; ni < 4; ++ni)
            b0[ni] = *(const bf16x8*)(wbc + boff[ni] + c * 128);
        #pragma unroll
        for (int ni = 0; ni < 4; ++ni)
            b1[ni] = *(const bf16x8*)(wbc + boff[ni] + c * 128 + 64);

        // ---- prefetch next chunk's A into the other buffer (stays in flight) ----
        if (c < 9) STAGEA(cur ^ 1, c + 1);

        // ---- A fragments from LDS (lgkmcnt path, independent of vmem queue) ----
        bf16x8 a0[4], a1[4];
        #pragma unroll
        for (int mi = 0; mi < 4; ++mi) {
            int ar = wr * 64 + mi * 16 + l16;
            a0[mi] = *(const bf16x8*)&Asm[cur][ar][((quad       ^ (l16 & 7)) << 3)];
            a1[mi] = *(const bf16x8*)&Asm[cur][ar][(((4 + quad) ^ (l16 & 7)) << 3)];
        }

        __builtin_amdgcn_s_setprio(1);
        #pragma unroll
        for (int mi = 0; mi < 4; ++mi)
            #pragma unroll
            for (int ni = 0; ni < 4; ++ni)
                acc[mi][ni] = __builtin_amdgcn_mfma_f32_16x16x32_bf16(
                                  a0[mi], b0[ni], acc[mi][ni], 0, 0, 0);
        #pragma unroll
        for (int mi = 0; mi < 4; ++mi)
            #pragma unroll
            for (int ni = 0; ni < 4; ++ni)
                acc[mi][ni] = __builtin_amdgcn_mfma_f32_16x16x32_bf16(
                                  a1[mi], b1[ni], acc[mi][ni], 0, 0, 0);
        __builtin_amdgcn_s_setprio(0);
    }
    #undef STAGEA

    // ---- epilogue: C layout col=lane&15, row=quad*4+reg; non-temporal stores ----
    float bv[4];
    #pragma unroll
    for (int ni = 0; ni < 4; ++ni) bv[ni] = bias[wc * 64 + ni * 16 + l16];

    #pragma unroll
    for (int mi = 0; mi < 4; ++mi) {
        #pragma unroll
        for (int r = 0; r < 4; ++r) {
            int row = m0 + wr * 64 + mi * 16 + quad * 4 + r;
            if (row < N) {
                #pragma unroll
                for (int ni = 0; ni < 4; ++ni) {
                    int n = wc * 64 + ni * 16 + l16;
                    __builtin_nontemporal_store(acc[mi][ni][r] + bv[ni],
                                                &out[(long)row * FOUT + n]);
                }
            }
        }
    }
}

// ---------------- round-1 fallback (used only if ws_size too small) ----------------
#define FBM 64
#define LDA 136
__global__ __launch_bounds__(256)
void mcc_fallback(const float* __restrict__ x, const int* __restrict__ nbr,
                  const float* __restrict__ W, const float* __restrict__ bias,
                  float* __restrict__ out, int N)
{
    __shared__ __align__(16) bf16 As[FBM][LDA];
    __shared__ __align__(16) bf16 Bs[FOUT][LDA];
    const int tid = threadIdx.x;
    const int m0 = blockIdx.x * FBM;
    const int wave = tid >> 6, lane = tid & 63, quad = lane >> 4, l16 = lane & 15;
    f32x4 acc[8] = {};
    const int arow = tid >> 2, asub = tid & 3, brow = tid >> 1, bhalf = tid & 1;
    for (int j = 0; j < 5; ++j) {
        {
            const float4* src = (const float4*)(W + (long)brow * FANIN + j * FIN + bhalf * 64);
            bf16* dst = &Bs[brow][bhalf * 64];
            #pragma unroll
            for (int i = 0; i < 16; ++i) {
                float4 v = src[i];
                dst[i*4+0]=(bf16)v.x; dst[i*4+1]=(bf16)v.y; dst[i*4+2]=(bf16)v.z; dst[i*4+3]=(bf16)v.w;
            }
        }
        {
            int node = m0 + arow; int nc = node < N ? node : N - 1;
            long long g = (j == 0) ? (long long)nc : (long long)nbr[(long long)nc * 4 + (j - 1)];
            const float4* src = (const float4*)(x + g * FIN);
            #pragma unroll
            for (int i = 0; i < 8; ++i) {
                int c4 = asub + i * 4;
                float4 v = src[c4];
                bf16* dst = &As[arow][c4 * 4];
                dst[0]=(bf16)v.x; dst[1]=(bf16)v.y; dst[2]=(bf16)v.z; dst[3]=(bf16)v.w;
            }
        }
        __syncthreads();
        #pragma unroll
        for (int kk = 0; kk < 4; ++kk) {
            bf16x8 a = *(const bf16x8*)&As[wave * 16 + l16][kk * 32 + quad * 8];
            #pragma unroll
            for (int nt = 0; nt < 8; ++nt) {
                bf16x8 b = *(const bf16x8*)&Bs[nt * 16 + l16][kk * 32 + quad * 8];
                acc[nt] = __builtin_amdgcn_mfma_f32_16x16x32_bf16(a, b, acc[nt], 0, 0, 0);
            }
        }
        __syncthreads();
    }
    const int m_local = wave * 16 + quad * 4;
    #pragma unroll
    for (int nt = 0; nt < 8; ++nt) {
        int n = nt * 16 + l16;
        float bvv = bias[n];
        #pragma unroll
        for (int r = 0; r < 4; ++r) {
            int node = m0 + m_local + r;
            if (node < N) out[(long)node * FOUT + n] = acc[nt][r] + bvv;
        }
    }
}

extern "C" void kernel_launch(void* const* d_in, const int* in_sizes, int n_in,
                              void* d_out, int out_size, void* d_ws, size_t ws_size,
                              hipStream_t stream) {
    const float* x    = (const float*)d_in[0];
    const int*   nbr  = (const int*)d_in[1];
    const float* W    = (const float*)d_in[2];
    const float* bias = (const float*)d_in[3];
    float* out = (float*)d_out;

    int N = in_sizes[0] / FIN;                              // 200000
    size_t xb_bytes = (size_t)N * FIN * sizeof(bf16);       // 51.2 MB
    size_t wb_bytes = (size_t)FOUT * FANIN * sizeof(bf16);  // 160 KB

    if (ws_size >= xb_bytes + wb_bytes) {
        bf16* xb = (bf16*)d_ws;
        bf16* wb = (bf16*)((char*)d_ws + xb_bytes);
        long nx4   = (long)N * FIN / 4;
        long ntot4 = nx4 + (long)FOUT * FANIN / 4;
        int cgrid = (int)((ntot4 + 255) / 256);
        convert_kernel<<<cgrid, 256, 0, stream>>>(x, W, xb, wb, nx4, ntot4);
        int grid = (N + BM - 1) / BM;                       // 1563
        mcc_mfma<<<grid, 256, 0, stream>>>(xb, nbr, wb, bias, out, N);
    } else {
        int grid = (N + FBM - 1) / FBM;
        mcc_fallback<<<grid, 256, 0, stream>>>(x, nbr, W, bias, out, N);
    }
}

// Round 3
// 239.034 us; speedup vs baseline: 1.3253x; 1.3253x over previous
//
#include <hip/hip_runtime.h>
#include <hip/hip_bf16.h>
#include <stdint.h>

typedef __bf16 bf16;
typedef bf16 bf16x4 __attribute__((ext_vector_type(4)));
typedef bf16 bf16x8 __attribute__((ext_vector_type(8)));
typedef float f32x4 __attribute__((ext_vector_type(4)));
typedef float fv4 __attribute__((ext_vector_type(4)));   // native clang vector for nontemporal builtins

#define FIN   128
#define FOUT  128
#define FANIN 640
#define BM    128
#define BK    32      // K sub-chunk (bf16 elems); A,B tiles 8KB each, full dbuf = 32KB total

__device__ __forceinline__ void async16(const void* g, void* l) {
    __builtin_amdgcn_global_load_lds((const __attribute__((address_space(1))) void*)g,
                                     (__attribute__((address_space(3))) void*)l,
                                     16, 0, 0);
}

// ---------------- convert fp32 -> bf16 (x and W), non-temporal reads ----------------
__global__ __launch_bounds__(256)
void convert_kernel(const float* __restrict__ x, const float* __restrict__ W,
                    bf16* __restrict__ xb, bf16* __restrict__ wb,
                    long nx4, long ntot4)
{
    long i = (long)blockIdx.x * 256 + threadIdx.x;   // float4 index
    if (i >= ntot4) return;
    fv4 v;
    bf16* dst;
    if (i < nx4) { v = __builtin_nontemporal_load((const fv4*)x + i); dst = xb + i * 4; }
    else         { long k = i - nx4;
                   v = __builtin_nontemporal_load((const fv4*)W + k); dst = wb + k * 4; }
    bf16x4 h = { (bf16)v.x, (bf16)v.y, (bf16)v.z, (bf16)v.w };
    *(bf16x4*)dst = h;
}

// ---------------- gather-GEMM v4: BK=32 full double-buffer in 32KB, 1 barrier/chunk ----------------
// Round-1 lesson: 64KB LDS halves blocks/CU (regressed). Round-2 lesson: B-from-global
// blows the register budget -> scratch spills (WRITE_SIZE 3x). v4 keeps BOTH resources at
// round-0 levels: BK=32 makes A,B tiles 8KB each so a full double-buffer of both is 32KB
// (5 blocks/CU), and one K-step per chunk keeps live operands at a[4]+b[4]=32 VGPRs.
// Schedule (T3 minimum 2-phase): top of chunk c waits vmcnt(0) on loads issued a FULL
// compute phase earlier (cheap), barrier, immediately issue chunk c+1's stage into buf^1,
// then ds_read + 16 MFMA. WAR on buf[cur] is covered by the same top barrier.
// At 64B row stride the fragment reads hit all 32 banks at minimum rounds: no swizzle,
// staging stays linear (global_load_lds requirement).
__global__ __launch_bounds__(256)
void mcc_mfma(const bf16* __restrict__ xb, const int* __restrict__ nbr,
              const bf16* __restrict__ wb, const float* __restrict__ bias,
              float* __restrict__ out, int N)
{
    __shared__ __align__(16) bf16 Asm[2][BM][BK];     // 16 KB
    __shared__ __align__(16) bf16 Bsm[2][FOUT][BK];   // 16 KB

    const int tid  = threadIdx.x;
    const int wave = tid >> 6;
    const int lane = tid & 63;
    const int quad = lane >> 4;
    const int l16  = lane & 15;
    const int wr   = wave >> 1;      // wave row 0..1 (64 out-rows each)
    const int wc   = wave & 1;       // wave col 0..1 (64 out-cols each)
    const int m0   = blockIdx.x * BM;

    const int r4 = lane >> 2;        // row-within-staging-instr 0..15 (16 rows x 64B = 1KB)
    const int c4 = lane & 3;         // 16B chunk 0..3 within a 64B row slice

    // preload gather row ids into VGPRs: gsel[i][j], i = staging instr (16 rows), j = slot
    int gsel[2][5];
    #pragma unroll
    for (int i = 0; i < 2; ++i) {
        int node = m0 + wave * 32 + i * 16 + r4;
        node = node < N ? node : N - 1;
        gsel[i][0] = node;
        #pragma unroll
        for (int jj = 1; jj < 5; ++jj)
            gsel[i][jj] = nbr[(long)node * 4 + (jj - 1)];   // 4 lanes share addr (broadcast)
    }
    // drain nbr loads so the only outstanding VMEM ops in the loop are our async16s
    asm volatile("s_waitcnt vmcnt(0)" ::: "memory");

    f32x4 acc[4][4] = {};

    // stage chunk k (j = k>>2 gather slot, h = k&3 64B quarter of the 256B row) into buf pb:
    // 2 A + 2 B async16 per wave, each staging 16 rows (lane l -> row l>>2, 16B chunk l&3)
    #define STAGE(pb, k) do {                                                              \
        const int j_ = (k) >> 2, h_ = (k) & 3;                                             \
        _Pragma("unroll")                                                                  \
        for (int i = 0; i < 2; ++i) {                                                      \
            const char* ga = (const char*)xb + ((long)gsel[i][j_] << 8)                    \
                             + h_ * 64 + c4 * 16;                                          \
            async16(ga, &Asm[pb][wave * 32 + i * 16][0]);                                  \
        }                                                                                  \
        _Pragma("unroll")                                                                  \
        for (int i = 0; i < 2; ++i) {                                                      \
            int br_ = wave * 32 + i * 16 + r4;                                             \
            const char* gb = (const char*)wb + (long)br_ * (FANIN * 2)                     \
                             + (k) * 64 + c4 * 16;                                         \
            async16(gb, &Bsm[pb][wave * 32 + i * 16][0]);                                  \
        }                                                                                  \
    } while (0)

    STAGE(0, 0);

    #pragma unroll
    for (int c = 0; c < 20; ++c) {
        const int cur = c & 1;

        // buf[cur]'s 4 loads were issued one full compute phase ago -> cheap wait
        asm volatile("s_waitcnt vmcnt(0)" ::: "memory");
        __builtin_amdgcn_s_barrier();               // data visible to all; buf[cur^1] reads done
        asm volatile("" ::: "memory");

        // issue next chunk's stage immediately (in flight across the whole compute phase)
        if (c < 19) STAGE(cur ^ 1, c + 1);

        // fragments: row = l16-selected, k-group = quad (8 contiguous bf16 = 16B)
        bf16x8 a[4], b[4];
        #pragma unroll
        for (int mi = 0; mi < 4; ++mi) {
            int ar = wr * 64 + mi * 16 + l16;
            a[mi] = *(const bf16x8*)&Asm[cur][ar][quad * 8];
        }
        #pragma unroll
        for (int ni = 0; ni < 4; ++ni) {
            int br = wc * 64 + ni * 16 + l16;
            b[ni] = *(const bf16x8*)&Bsm[cur][br][quad * 8];
        }

        __builtin_amdgcn_s_setprio(1);
        #pragma unroll
        for (int mi = 0; mi < 4; ++mi)
            #pragma unroll
            for (int ni = 0; ni < 4; ++ni)
                acc[mi][ni] = __builtin_amdgcn_mfma_f32_16x16x32_bf16(
                                  a[mi], b[ni], acc[mi][ni], 0, 0, 0);
        __builtin_amdgcn_s_setprio(0);
    }
    #undef STAGE

    // ---- epilogue: C layout col=lane&15, row=quad*4+reg; non-temporal stores ----
    float bv[4];
    #pragma unroll
    for (int ni = 0; ni < 4; ++ni) bv[ni] = bias[wc * 64 + ni * 16 + l16];

    #pragma unroll
    for (int mi = 0; mi < 4; ++mi) {
        #pragma unroll
        for (int r = 0; r < 4; ++r) {
            int row = m0 + wr * 64 + mi * 16 + quad * 4 + r;
            if (row < N) {
                #pragma unroll
                for (int ni = 0; ni < 4; ++ni) {
                    int n = wc * 64 + ni * 16 + l16;
                    __builtin_nontemporal_store(acc[mi][ni][r] + bv[ni],
                                                &out[(long)row * FOUT + n]);
                }
            }
        }
    }
}

// ---------------- round-1 fallback (used only if ws_size too small) ----------------
#define FBM 64
#define LDA 136
__global__ __launch_bounds__(256)
void mcc_fallback(const float* __restrict__ x, const int* __restrict__ nbr,
                  const float* __restrict__ W, const float* __restrict__ bias,
                  float* __restrict__ out, int N)
{
    __shared__ __align__(16) bf16 As[FBM][LDA];
    __shared__ __align__(16) bf16 Bs[FOUT][LDA];
    const int tid = threadIdx.x;
    const int m0 = blockIdx.x * FBM;
    const int wave = tid >> 6, lane = tid & 63, quad = lane >> 4, l16 = lane & 15;
    f32x4 acc[8] = {};
    const int arow = tid >> 2, asub = tid & 3, brow = tid >> 1, bhalf = tid & 1;
    for (int j = 0; j < 5; ++j) {
        {
            const float4* src = (const float4*)(W + (long)brow * FANIN + j * FIN + bhalf * 64);
            bf16* dst = &Bs[brow][bhalf * 64];
            #pragma unroll
            for (int i = 0; i < 16; ++i) {
                float4 v = src[i];
                dst[i*4+0]=(bf16)v.x; dst[i*4+1]=(bf16)v.y; dst[i*4+2]=(bf16)v.z; dst[i*4+3]=(bf16)v.w;
            }
        }
        {
            int node = m0 + arow; int nc = node < N ? node : N - 1;
            long long g = (j == 0) ? (long long)nc : (long long)nbr[(long long)nc * 4 + (j - 1)];
            const float4* src = (const float4*)(x + g * FIN);
            #pragma unroll
            for (int i = 0; i < 8; ++i) {
                int c4 = asub + i * 4;
                float4 v = src[c4];
                bf16* dst = &As[arow][c4 * 4];
                dst[0]=(bf16)v.x; dst[1]=(bf16)v.y; dst[2]=(bf16)v.z; dst[3]=(bf16)v.w;
            }
        }
        __syncthreads();
        #pragma unroll
        for (int kk = 0; kk < 4; ++kk) {
            bf16x8 a = *(const bf16x8*)&As[wave * 16 + l16][kk * 32 + quad * 8];
            #pragma unroll
            for (int nt = 0; nt < 8; ++nt) {
                bf16x8 b = *(const bf16x8*)&Bs[nt * 16 + l16][kk * 32 + quad * 8];
                acc[nt] = __builtin_amdgcn_mfma_f32_16x16x32_bf16(a, b, acc[nt], 0, 0, 0);
            }
        }
        __syncthreads();
    }
    const int m_local = wave * 16 + quad * 4;
    #pragma unroll
    for (int nt = 0; nt < 8; ++nt) {
        int n = nt * 16 + l16;
        float bvv = bias[n];
        #pragma unroll
        for (int r = 0; r < 4; ++r) {
            int node = m0 + m_local + r;
            if (node < N) out[(long)node * FOUT + n] = acc[nt][r] + bvv;
        }
    }
}

extern "C" void kernel_launch(void* const* d_in, const int* in_sizes, int n_in,
                              void* d_out, int out_size, void* d_ws, size_t ws_size,
                              hipStream_t stream) {
    const float* x    = (const float*)d_in[0];
    const int*   nbr  = (const int*)d_in[1];
    const float* W    = (const float*)d_in[2];
    const float* bias = (const float*)d_in[3];
    float* out = (float*)d_out;

    int N = in_sizes[0] / FIN;                              // 200000
    size_t xb_bytes = (size_t)N * FIN * sizeof(bf16);       // 51.2 MB
    size_t wb_bytes = (size_t)FOUT * FANIN * sizeof(bf16);  // 160 KB

    if (ws_size >= xb_bytes + wb_bytes) {
        bf16* xb = (bf16*)d_ws;
        bf16* wb = (bf16*)((char*)d_ws + xb_bytes);
        long nx4   = (long)N * FIN / 4;
        long ntot4 = nx4 + (long)FOUT * FANIN / 4;
        int cgrid = (int)((ntot4 + 255) / 256);
        convert_kernel<<<cgrid, 256, 0, stream>>>(x, W, xb, wb, nx4, ntot4);
        int grid = (N + BM - 1) / BM;                       // 1563
        mcc_mfma<<<grid, 256, 0, stream>>>(xb, nbr, wb, bias, out, N);
    } else {
        int grid = (N + FBM - 1) / FBM;
        mcc_fallback<<<grid, 256, 0, stream>>>(x, nbr, W, bias, out, N);
    }
}